// Round 4
// baseline (102.579 us; speedup 1.0000x reference)
//
#include <hip/hip_runtime.h>

#define NK 512
#define NC 256
#define NH 200
#define NW 200
#define PLANE (NH * NW)
#define RSCALE 0.0625f
#define GC 4           // channels per block
#define WIN_H 32       // max rows a roi's samples touch (span<31 incl. +1 corner)
#define WIN_W 36       // max cols incl. float4 window (34) rounded to 4
#define NCHK 9         // float4 chunks per staged row
#define WSTRIDE 38     // LDS row stride in floats (mod 32 = 6 -> ~2-way conflicts)
#define NCHUNK (GC * WIN_H * NCHK)   // 1152 = 18 full waves

// One block per (roi k, 4-channel group). 512 threads.
// Phase 0: 22 threads build per-bin weight/offset tables.
// Phase 1: all threads stage the 32x36 window x4 ch into LDS (float4 chunks).
// Phase 2: 484 threads = (ch, bin): pooled bin from 16 LDS reads + 20 FMAs.
// Phase 3: 100 threads 3x3/stride2 max-pool -> out, contiguous 100 floats.
__global__ __launch_bounds__(512) void roi_align_maxpool(
    const float* __restrict__ feat,   // (B, C, H, W) f32
    const float* __restrict__ rois,   // (K, 5)
    float* __restrict__ out)          // (K, C, 5, 5)
{
    __shared__ float s_win[GC * WIN_H * WSTRIDE];  // 19456 B
    __shared__ float s_W [11][4];      // combined x-weights (4-col window)
    __shared__ int   s_xoff[11];       // xb - xwin
    __shared__ int   s_yb[11][4];      // (row - ywin) * WSTRIDE
    __shared__ float s_wy[11][4];      // 0.25 * vy * (hy|ly)
    __shared__ float s_pool[GC][121];

    const int blk = blockIdx.x;
    const int k   = blk % NK;          // roi fastest: co-resident blocks share planes in L2
    const int cg  = blk / NK;
    const int t   = threadIdx.x;

    const float r0  = rois[k * 5 + 0];
    const float rx1 = rois[k * 5 + 1] * RSCALE;
    const float ry1 = rois[k * 5 + 2] * RSCALE;
    const float rx2 = rois[k * 5 + 3] * RSCALE;
    const float ry2 = rois[k * 5 + 4] * RSCALE;
    const int   b   = (int)r0;
    const float bin_w = fmaxf(rx2 - rx1, 1.0f) / 11.0f;
    const float bin_h = fmaxf(ry2 - ry1, 1.0f) / 11.0f;

    // Window origin — every thread computes (needed by staging).
    // Same expression order as the table phase so floor() agrees bitwise.
    float cx0 = rx1 + (0.0f + 0.25f) * bin_w;
    cx0 = fminf(fmaxf(cx0, 0.0f), (float)(NW - 1));
    const int xwin = min((int)floorf(cx0), NW - WIN_W);
    float cy0 = ry1 + (0.0f + 0.25f) * bin_h;
    cy0 = fminf(fmaxf(cy0, 0.0f), (float)(NH - 1));
    const int ywin = min((int)floorf(cy0), NH - WIN_H);

    if (t < 22) {
        const int d = t / 11;          // 0 = x, 1 = y
        const int pbin = t % 11;
        const float start = d ? ry1 : rx1;
        const float bs    = d ? bin_h : bin_w;
        const int   lim   = d ? NH : NW;
        const float p = (float)pbin;
        float cv0 = start + (p + 0.25f) * bs;   // (0+0.5)/2
        float cv1 = start + (p + 0.75f) * bs;   // (1+0.5)/2
        const float va0 = (cv0 > -1.0f && cv0 < (float)lim) ? 1.0f : 0.0f;
        const float va1 = (cv1 > -1.0f && cv1 < (float)lim) ? 1.0f : 0.0f;
        cv0 = fminf(fmaxf(cv0, 0.0f), (float)(lim - 1));
        cv1 = fminf(fmaxf(cv1, 0.0f), (float)(lim - 1));
        const int lo0 = (int)floorf(cv0);
        const int lo1 = (int)floorf(cv1);
        const int hi0 = min(lo0 + 1, lim - 1);
        const int hi1 = min(lo1 + 1, lim - 1);
        const float fr0 = cv0 - (float)lo0;
        const float fr1 = cv1 - (float)lo1;
        if (d == 0) {
            const int xb = min(lo0, NW - 4);     // 4-col window base
            s_xoff[pbin] = xb - xwin;            // in [0, 32]
            s_W[pbin][0] = 0.0f; s_W[pbin][1] = 0.0f;
            s_W[pbin][2] = 0.0f; s_W[pbin][3] = 0.0f;
            s_W[pbin][lo0 - xb] += va0 * (1.0f - fr0);
            s_W[pbin][hi0 - xb] += va0 * fr0;
            s_W[pbin][lo1 - xb] += va1 * (1.0f - fr1);
            s_W[pbin][hi1 - xb] += va1 * fr1;
        } else {
            s_yb[pbin][0] = (lo0 - ywin) * WSTRIDE;   // rows in [ywin, ywin+31]
            s_yb[pbin][1] = (hi0 - ywin) * WSTRIDE;
            s_yb[pbin][2] = (lo1 - ywin) * WSTRIDE;
            s_yb[pbin][3] = (hi1 - ywin) * WSTRIDE;
            s_wy[pbin][0] = 0.25f * va0 * (1.0f - fr0);
            s_wy[pbin][1] = 0.25f * va0 * fr0;
            s_wy[pbin][2] = 0.25f * va1 * (1.0f - fr1);
            s_wy[pbin][3] = 0.25f * va1 * fr1;
        }
    }
    __syncthreads();

    // Phase 1: stage window. 1152 float4 chunks, 512 threads, 3 steps
    // (loads issued first, writes after -> latency overlapped).
    {
        const float* fbase = feat + (size_t)(b * NC + cg * GC) * PLANE;
        const int q0 = t, q1 = t + 512, q2 = t + 1024;
        #define CHSRC(q) (fbase + (size_t)((q) / (WIN_H * NCHK)) * PLANE \
                          + (ywin + (((q) / NCHK) % WIN_H)) * NW + (xwin + 4 * ((q) % NCHK)))
        #define CHDST(q) (s_win + (((q) / NCHK)) * WSTRIDE + 4 * ((q) % NCHK))
        const float4 v0 = *(const float4*)CHSRC(q0);
        const float4 v1 = *(const float4*)CHSRC(q1);
        float4 v2;
        if (q2 < NCHUNK) v2 = *(const float4*)CHSRC(q2);
        float* d0p = CHDST(q0);
        ((float2*)d0p)[0] = make_float2(v0.x, v0.y);
        ((float2*)d0p)[1] = make_float2(v0.z, v0.w);
        float* d1p = CHDST(q1);
        ((float2*)d1p)[0] = make_float2(v1.x, v1.y);
        ((float2*)d1p)[1] = make_float2(v1.z, v1.w);
        if (q2 < NCHUNK) {
            float* d2p = CHDST(q2);
            ((float2*)d2p)[0] = make_float2(v2.x, v2.y);
            ((float2*)d2p)[1] = make_float2(v2.z, v2.w);
        }
        #undef CHSRC
        #undef CHDST
    }
    __syncthreads();

    if (t < 484) {
        const int ch  = t / 121;
        const int bin = t - ch * 121;
        const int ph  = bin / 11, pw = bin - ph * 11;

        const float4 W  = *(const float4*)s_W[pw];
        const float4 wy = *(const float4*)s_wy[ph];
        const int4   yb = *(const int4*)s_yb[ph];
        const float* wb = s_win + ch * (WIN_H * WSTRIDE) + s_xoff[pw];

        const float* p0 = wb + yb.x;
        const float* p1 = wb + yb.y;
        const float* p2 = wb + yb.z;
        const float* p3 = wb + yb.w;

        float d0 = p0[0] * W.x; d0 = fmaf(p0[1], W.y, d0); d0 = fmaf(p0[2], W.z, d0); d0 = fmaf(p0[3], W.w, d0);
        float d1 = p1[0] * W.x; d1 = fmaf(p1[1], W.y, d1); d1 = fmaf(p1[2], W.z, d1); d1 = fmaf(p1[3], W.w, d1);
        float d2 = p2[0] * W.x; d2 = fmaf(p2[1], W.y, d2); d2 = fmaf(p2[2], W.z, d2); d2 = fmaf(p2[3], W.w, d2);
        float d3 = p3[0] * W.x; d3 = fmaf(p3[1], W.y, d3); d3 = fmaf(p3[2], W.z, d3); d3 = fmaf(p3[3], W.w, d3);

        float bsum = wy.x * d0;
        bsum = fmaf(wy.y, d1, bsum);
        bsum = fmaf(wy.z, d2, bsum);
        bsum = fmaf(wy.w, d3, bsum);

        s_pool[ch][bin] = bsum;   // 0.25 mean folded into wy
    }
    __syncthreads();

    if (t < 100) {
        const int ch = t / 25;
        const int r  = t % 25;
        const int oh = r / 5, ow = r % 5;
        float m = -INFINITY;
        #pragma unroll
        for (int dy = 0; dy < 3; ++dy)
            #pragma unroll
            for (int dx = 0; dx < 3; ++dx)
                m = fmaxf(m, s_pool[ch][(2 * oh + dy) * 11 + (2 * ow + dx)]);
        out[((size_t)k * NC + cg * GC) * 25 + t] = m;
    }
}

extern "C" void kernel_launch(void* const* d_in, const int* in_sizes, int n_in,
                              void* d_out, int out_size, void* d_ws, size_t ws_size,
                              hipStream_t stream) {
    const float* feat = (const float*)d_in[0];   // (4, 256, 200, 200) f32
    const float* rois = (const float*)d_in[1];   // (512, 5) f32
    float* out = (float*)d_out;                  // (512, 256, 5, 5) f32

    const int nblocks = NK * (NC / GC);          // 32768
    roi_align_maxpool<<<nblocks, 512, 0, stream>>>(feat, rois, out);
}

// Round 5
// 64.231 us; speedup vs baseline: 1.5970x; 1.5970x over previous
//
#include <hip/hip_runtime.h>

#define NK 512
#define NC 256
#define NH 200
#define NW 200
#define PLANE (NH * NW)
#define RSCALE 0.0625f
#define GC 8                 // channels per block
#define HGC 4                // pairing (ch, ch+4) per thread
#define MAXROWS 32           // max distinct sample rows per roi (span<=31 incl +1)
#define XROW (MAXROWS * 11)  // 352 xdot slots per channel
#define NPAIRA (HGC * XROW)  // 1408 max phase-A pair tasks
#define NPAIRB (HGC * 121)   // 484 phase-B pair tasks

// One block per (roi k, 8-channel group). 512 threads.
// Phase 0: 22 threads build per-bin tables (x: 4-col window + combined weights;
//          y: 4 row indices rel. to ymin (pre-scaled by 11) + weights w/ 0.25).
// Phase A: separable x-pass: xdot[ch][row][pw] = dot4(feat row window, W[pw]).
//          Pair tasks (ch,ch+4): 2 float4 gathers + 8 FMA each. <=3 iters.
// Phase B: bins: pooled = sum_r wy[r]*xdot[row_r][pw] (8 LDS reads, 8 FMA / pair).
// Phase C: 200 threads 3x3/stride2 max-pool -> out, contiguous 200 floats.
__global__ __launch_bounds__(512) void roi_align_maxpool(
    const float* __restrict__ feat,   // (B, C, H, W) f32
    const float* __restrict__ rois,   // (K, 5)
    float* __restrict__ out)          // (K, C, 5, 5)
{
    __shared__ float s_xdot[GC][XROW];   // 11264 B
    __shared__ float s_pool[GC][121];    // 3872 B
    __shared__ int   s_xb[11];           // absolute base col of 4-col window
    __shared__ float s_W [11][4];        // combined x-weights (validity folded)
    __shared__ int   s_yrel[11][4];      // (row - ymin) * 11  (xdot row stride)
    __shared__ float s_wy[11][4];        // 0.25 * vy * (hy|ly)

    const int blk = blockIdx.x;
    const int k   = blk % NK;            // roi fastest: co-resident blocks share planes in L2
    const int cg  = blk / NK;
    const int t   = threadIdx.x;

    const float r0  = rois[k * 5 + 0];
    const float rx1 = rois[k * 5 + 1] * RSCALE;
    const float ry1 = rois[k * 5 + 2] * RSCALE;
    const float rx2 = rois[k * 5 + 3] * RSCALE;
    const float ry2 = rois[k * 5 + 4] * RSCALE;
    const int   b   = (int)r0;
    const float bin_w = fmaxf(rx2 - rx1, 1.0f) / 11.0f;
    const float bin_h = fmaxf(ry2 - ry1, 1.0f) / 11.0f;

    // Uniform ymin/ymax: rows are monotone in (ph, sub), so min row is
    // lo0(ph=0) and max row is hi1(ph=10). Expressions must match phase 0
    // bitwise (same order: start + (p + g)*bs, clamp, floor).
    float cy0 = ry1 + (0.0f + 0.25f) * bin_h;
    cy0 = fminf(fmaxf(cy0, 0.0f), (float)(NH - 1));
    const int ymin = (int)floorf(cy0);
    float cyL = ry1 + (10.0f + 0.75f) * bin_h;
    cyL = fminf(fmaxf(cyL, 0.0f), (float)(NH - 1));
    const int ymax = min((int)floorf(cyL) + 1, NH - 1);
    const int nrows = ymax - ymin + 1;   // 2..32

    if (t < 22) {
        const int d = t / 11;            // 0 = x, 1 = y
        const int pbin = t % 11;
        const float start = d ? ry1 : rx1;
        const float bs    = d ? bin_h : bin_w;
        const int   lim   = d ? NH : NW;
        const float p = (float)pbin;
        float cv0 = start + (p + 0.25f) * bs;   // (0+0.5)/2
        float cv1 = start + (p + 0.75f) * bs;   // (1+0.5)/2
        const float va0 = (cv0 > -1.0f && cv0 < (float)lim) ? 1.0f : 0.0f;
        const float va1 = (cv1 > -1.0f && cv1 < (float)lim) ? 1.0f : 0.0f;
        cv0 = fminf(fmaxf(cv0, 0.0f), (float)(lim - 1));
        cv1 = fminf(fmaxf(cv1, 0.0f), (float)(lim - 1));
        const int lo0 = (int)floorf(cv0);
        const int lo1 = (int)floorf(cv1);
        const int hi0 = min(lo0 + 1, lim - 1);
        const int hi1 = min(lo1 + 1, lim - 1);
        const float fr0 = cv0 - (float)lo0;
        const float fr1 = cv1 - (float)lo1;
        if (d == 0) {
            const int xb = min(lo0, NW - 4);    // 4-col window base (lo1<=lo0+2)
            s_xb[pbin] = xb;
            s_W[pbin][0] = 0.0f; s_W[pbin][1] = 0.0f;
            s_W[pbin][2] = 0.0f; s_W[pbin][3] = 0.0f;
            s_W[pbin][lo0 - xb] += va0 * (1.0f - fr0);
            s_W[pbin][hi0 - xb] += va0 * fr0;
            s_W[pbin][lo1 - xb] += va1 * (1.0f - fr1);
            s_W[pbin][hi1 - xb] += va1 * fr1;
        } else {
            s_yrel[pbin][0] = (lo0 - ymin) * 11;
            s_yrel[pbin][1] = (hi0 - ymin) * 11;
            s_yrel[pbin][2] = (lo1 - ymin) * 11;
            s_yrel[pbin][3] = (hi1 - ymin) * 11;
            s_wy[pbin][0] = 0.25f * va0 * (1.0f - fr0);
            s_wy[pbin][1] = 0.25f * va0 * fr0;
            s_wy[pbin][2] = 0.25f * va1 * (1.0f - fr1);
            s_wy[pbin][3] = 0.25f * va1 * fr1;
        }
    }
    __syncthreads();

    // Phase A: xdot for every needed (ch-pair, row, pw)
    {
        const float* fbase = feat + (size_t)(b * NC + cg * GC) * PLANE;
        #pragma unroll
        for (int i = 0; i < 3; ++i) {
            const int q = t + 512 * i;
            if (q < NPAIRA) {                       // i<2 always true (const-folded)
                const int ch4 = q / XROW;           // 0..3  -> channels ch4, ch4+4
                const int rem = q - ch4 * XROW;
                const int rel = rem / 11;
                const int pw  = rem - rel * 11;
                if (rel < nrows) {
                    const int    xb = s_xb[pw];
                    const float4 W  = *(const float4*)s_W[pw];
                    const float* p0 = fbase + (size_t)ch4 * PLANE + (ymin + rel) * NW + xb;
                    const float4 v0 = *(const float4*)p0;             // ch = ch4
                    const float4 v1 = *(const float4*)(p0 + 4 * PLANE); // ch = ch4+4
                    float d0 = v0.x * W.x; d0 = fmaf(v0.y, W.y, d0); d0 = fmaf(v0.z, W.z, d0); d0 = fmaf(v0.w, W.w, d0);
                    float d1 = v1.x * W.x; d1 = fmaf(v1.y, W.y, d1); d1 = fmaf(v1.z, W.z, d1); d1 = fmaf(v1.w, W.w, d1);
                    s_xdot[ch4    ][rem] = d0;
                    s_xdot[ch4 + 4][rem] = d1;
                }
            }
        }
    }
    __syncthreads();

    // Phase B: combine 4 xdots per bin (pairing ch, ch+4)
    if (t < NPAIRB) {
        const int ch4 = t / 121;
        const int bin = t - ch4 * 121;
        const int ph  = bin / 11;
        const int pw  = bin - ph * 11;
        const int4   yr = *(const int4*)s_yrel[ph];
        const float4 wy = *(const float4*)s_wy[ph];
        const float* xd0 = &s_xdot[ch4    ][pw];
        const float* xd1 = &s_xdot[ch4 + 4][pw];
        float b0 = wy.x * xd0[yr.x];
        b0 = fmaf(wy.y, xd0[yr.y], b0);
        b0 = fmaf(wy.z, xd0[yr.z], b0);
        b0 = fmaf(wy.w, xd0[yr.w], b0);
        float b1 = wy.x * xd1[yr.x];
        b1 = fmaf(wy.y, xd1[yr.y], b1);
        b1 = fmaf(wy.z, xd1[yr.z], b1);
        b1 = fmaf(wy.w, xd1[yr.w], b1);
        s_pool[ch4    ][bin] = b0;   // 0.25 mean folded into wy
        s_pool[ch4 + 4][bin] = b1;
    }
    __syncthreads();

    // Phase C: 3x3/stride2 max-pool, contiguous 200-float store per block
    if (t < GC * 25) {
        const int ch = t / 25;
        const int r  = t % 25;
        const int oh = r / 5, ow = r % 5;
        float m = -INFINITY;
        #pragma unroll
        for (int dy = 0; dy < 3; ++dy)
            #pragma unroll
            for (int dx = 0; dx < 3; ++dx)
                m = fmaxf(m, s_pool[ch][(2 * oh + dy) * 11 + (2 * ow + dx)]);
        out[((size_t)k * NC + cg * GC) * 25 + t] = m;
    }
}

extern "C" void kernel_launch(void* const* d_in, const int* in_sizes, int n_in,
                              void* d_out, int out_size, void* d_ws, size_t ws_size,
                              hipStream_t stream) {
    const float* feat = (const float*)d_in[0];   // (4, 256, 200, 200) f32
    const float* rois = (const float*)d_in[1];   // (512, 5) f32
    float* out = (float*)d_out;                  // (512, 256, 5, 5) f32

    const int nblocks = NK * (NC / GC);          // 16384
    roi_align_maxpool<<<nblocks, 512, 0, stream>>>(feat, rois, out);
}

// Round 6
// 53.184 us; speedup vs baseline: 1.9288x; 1.2077x over previous
//
#include <hip/hip_runtime.h>

#define NK 512
#define NC 256
#define NH 200
#define NW 200
#define PLANE (NH * NW)
#define RSCALE 0.0625f
#define GC 8                 // channels per block
#define HGC 4                // pairing (ch, ch+4) per thread
#define MAXROWS 32           // max distinct sample rows per roi (span<=31 incl +1)
#define XROW (MAXROWS * 11)  // 352 xdot slots per channel
#define NPAIRA (HGC * XROW)  // 1408 max phase-A pair tasks
#define NPAIRB (HGC * 121)   // 484 phase-B pair tasks

// One block per (roi k, 8-channel group). 512 threads.
// XCD-affinity block mapping: dispatch round-robins blockIdx across the 8 XCDs
// (blk % 8 -> XCD). We pin each channel-group to ONE XCD so every feature line
// is owned by a single XCD's L2: xcd = blk&7, k fast within XCD, cg = local*8+xcd.
// Cross-roi re-reads (the 3x overlap factor) then hit per-XCD L2 instead of L3.
// Phase 0: 22 threads build per-bin tables.
// Phase A: separable x-pass: xdot[ch][row][pw] = dot4(feat row window, W[pw]).
// Phase B: pooled bin = sum_r wy[r]*xdot[row_r][pw].
// Phase C: 200 threads 3x3/stride2 max-pool -> out, contiguous 200 floats.
__global__ __launch_bounds__(512) void roi_align_maxpool(
    const float* __restrict__ feat,   // (B, C, H, W) f32
    const float* __restrict__ rois,   // (K, 5)
    float* __restrict__ out)          // (K, C, 5, 5)
{
    __shared__ float s_xdot[GC][XROW];   // 11264 B
    __shared__ float s_pool[GC][121];    // 3872 B
    __shared__ int   s_xb[11];           // absolute base col of 4-col window
    __shared__ float s_W [11][4];        // combined x-weights (validity folded)
    __shared__ int   s_yrel[11][4];      // (row - ymin) * 11  (xdot row stride)
    __shared__ float s_wy[11][4];        // 0.25 * vy * (hy|ly)

    const int blk = blockIdx.x;
    const int xcd = blk & 7;             // dispatch: blk % 8 -> XCD id
    const int j   = blk >> 3;
    const int k   = j & (NK - 1);        // roi, fast within an XCD's stream
    const int cg  = ((j >> 9) << 3) | xcd;   // channel-group pinned to this XCD
    const int t   = threadIdx.x;

    const float r0  = rois[k * 5 + 0];
    const float rx1 = rois[k * 5 + 1] * RSCALE;
    const float ry1 = rois[k * 5 + 2] * RSCALE;
    const float rx2 = rois[k * 5 + 3] * RSCALE;
    const float ry2 = rois[k * 5 + 4] * RSCALE;
    const int   b   = (int)r0;
    const float bin_w = fmaxf(rx2 - rx1, 1.0f) / 11.0f;
    const float bin_h = fmaxf(ry2 - ry1, 1.0f) / 11.0f;

    // Uniform ymin/ymax: rows are monotone in (ph, sub); expressions match
    // phase 0 bitwise (same order: start + (p + g)*bs, clamp, floor).
    float cy0 = ry1 + (0.0f + 0.25f) * bin_h;
    cy0 = fminf(fmaxf(cy0, 0.0f), (float)(NH - 1));
    const int ymin = (int)floorf(cy0);
    float cyL = ry1 + (10.0f + 0.75f) * bin_h;
    cyL = fminf(fmaxf(cyL, 0.0f), (float)(NH - 1));
    const int ymax = min((int)floorf(cyL) + 1, NH - 1);
    const int nrows = ymax - ymin + 1;   // 2..32

    if (t < 22) {
        const int d = t / 11;            // 0 = x, 1 = y
        const int pbin = t % 11;
        const float start = d ? ry1 : rx1;
        const float bs    = d ? bin_h : bin_w;
        const int   lim   = d ? NH : NW;
        const float p = (float)pbin;
        float cv0 = start + (p + 0.25f) * bs;   // (0+0.5)/2
        float cv1 = start + (p + 0.75f) * bs;   // (1+0.5)/2
        const float va0 = (cv0 > -1.0f && cv0 < (float)lim) ? 1.0f : 0.0f;
        const float va1 = (cv1 > -1.0f && cv1 < (float)lim) ? 1.0f : 0.0f;
        cv0 = fminf(fmaxf(cv0, 0.0f), (float)(lim - 1));
        cv1 = fminf(fmaxf(cv1, 0.0f), (float)(lim - 1));
        const int lo0 = (int)floorf(cv0);
        const int lo1 = (int)floorf(cv1);
        const int hi0 = min(lo0 + 1, lim - 1);
        const int hi1 = min(lo1 + 1, lim - 1);
        const float fr0 = cv0 - (float)lo0;
        const float fr1 = cv1 - (float)lo1;
        if (d == 0) {
            const int xb = min(lo0, NW - 4);    // 4-col window base (lo1<=lo0+2)
            s_xb[pbin] = xb;
            s_W[pbin][0] = 0.0f; s_W[pbin][1] = 0.0f;
            s_W[pbin][2] = 0.0f; s_W[pbin][3] = 0.0f;
            s_W[pbin][lo0 - xb] += va0 * (1.0f - fr0);
            s_W[pbin][hi0 - xb] += va0 * fr0;
            s_W[pbin][lo1 - xb] += va1 * (1.0f - fr1);
            s_W[pbin][hi1 - xb] += va1 * fr1;
        } else {
            s_yrel[pbin][0] = (lo0 - ymin) * 11;
            s_yrel[pbin][1] = (hi0 - ymin) * 11;
            s_yrel[pbin][2] = (lo1 - ymin) * 11;
            s_yrel[pbin][3] = (hi1 - ymin) * 11;
            s_wy[pbin][0] = 0.25f * va0 * (1.0f - fr0);
            s_wy[pbin][1] = 0.25f * va0 * fr0;
            s_wy[pbin][2] = 0.25f * va1 * (1.0f - fr1);
            s_wy[pbin][3] = 0.25f * va1 * fr1;
        }
    }
    __syncthreads();

    // Phase A: xdot for every needed (ch-pair, row, pw)
    {
        const float* fbase = feat + (size_t)(b * NC + cg * GC) * PLANE;
        #pragma unroll
        for (int i = 0; i < 3; ++i) {
            const int q = t + 512 * i;
            if (q < NPAIRA) {                       // i<2 always true (const-folded)
                const int ch4 = q / XROW;           // 0..3  -> channels ch4, ch4+4
                const int rem = q - ch4 * XROW;
                const int rel = rem / 11;
                const int pw  = rem - rel * 11;
                if (rel < nrows) {
                    const int    xb = s_xb[pw];
                    const float4 W  = *(const float4*)s_W[pw];
                    const float* p0 = fbase + (size_t)ch4 * PLANE + (ymin + rel) * NW + xb;
                    const float4 v0 = *(const float4*)p0;               // ch = ch4
                    const float4 v1 = *(const float4*)(p0 + 4 * PLANE); // ch = ch4+4
                    float d0 = v0.x * W.x; d0 = fmaf(v0.y, W.y, d0); d0 = fmaf(v0.z, W.z, d0); d0 = fmaf(v0.w, W.w, d0);
                    float d1 = v1.x * W.x; d1 = fmaf(v1.y, W.y, d1); d1 = fmaf(v1.z, W.z, d1); d1 = fmaf(v1.w, W.w, d1);
                    s_xdot[ch4    ][rem] = d0;
                    s_xdot[ch4 + 4][rem] = d1;
                }
            }
        }
    }
    __syncthreads();

    // Phase B: combine 4 xdots per bin (pairing ch, ch+4)
    if (t < NPAIRB) {
        const int ch4 = t / 121;
        const int bin = t - ch4 * 121;
        const int ph  = bin / 11;
        const int pw  = bin - ph * 11;
        const int4   yr = *(const int4*)s_yrel[ph];
        const float4 wy = *(const float4*)s_wy[ph];
        const float* xd0 = &s_xdot[ch4    ][pw];
        const float* xd1 = &s_xdot[ch4 + 4][pw];
        float b0 = wy.x * xd0[yr.x];
        b0 = fmaf(wy.y, xd0[yr.y], b0);
        b0 = fmaf(wy.z, xd0[yr.z], b0);
        b0 = fmaf(wy.w, xd0[yr.w], b0);
        float b1 = wy.x * xd1[yr.x];
        b1 = fmaf(wy.y, xd1[yr.y], b1);
        b1 = fmaf(wy.z, xd1[yr.z], b1);
        b1 = fmaf(wy.w, xd1[yr.w], b1);
        s_pool[ch4    ][bin] = b0;   // 0.25 mean folded into wy
        s_pool[ch4 + 4][bin] = b1;
    }
    __syncthreads();

    // Phase C: 3x3/stride2 max-pool, contiguous 200-float store per block
    if (t < GC * 25) {
        const int ch = t / 25;
        const int r  = t % 25;
        const int oh = r / 5, ow = r % 5;
        float m = -INFINITY;
        #pragma unroll
        for (int dy = 0; dy < 3; ++dy)
            #pragma unroll
            for (int dx = 0; dx < 3; ++dx)
                m = fmaxf(m, s_pool[ch][(2 * oh + dy) * 11 + (2 * ow + dx)]);
        out[((size_t)k * NC + cg * GC) * 25 + t] = m;
    }
}

extern "C" void kernel_launch(void* const* d_in, const int* in_sizes, int n_in,
                              void* d_out, int out_size, void* d_ws, size_t ws_size,
                              hipStream_t stream) {
    const float* feat = (const float*)d_in[0];   // (4, 256, 200, 200) f32
    const float* rois = (const float*)d_in[1];   // (512, 5) f32
    float* out = (float*)d_out;                  // (512, 256, 5, 5) f32

    const int nblocks = NK * (NC / GC);          // 16384
    roi_align_maxpool<<<nblocks, 512, 0, stream>>>(feat, rois, out);
}